// Round 19
// baseline (178.215 us; speedup 1.0000x reference)
//
#include <hip/hip_runtime.h>
#include <hip/hip_bf16.h>
#include <stdint.h>

#define B 4
#define S 2048
#define D 1024
#define H 16
#define DH 64
#define M_TOT (B*S)
#define BH (B*H)

typedef unsigned short u16;
typedef unsigned int u32;
typedef __attribute__((ext_vector_type(4))) float f32x4;
typedef __attribute__((ext_vector_type(16))) float f32x16;
typedef __attribute__((ext_vector_type(8))) short bf16x8;
typedef __attribute__((ext_vector_type(2))) unsigned int u32x2;

typedef const __attribute__((address_space(1))) unsigned int* gp_t;
typedef __attribute__((address_space(3))) unsigned int* lp_t;

__device__ __forceinline__ void gload_lds16(const void* g, void* l) {
    __builtin_amdgcn_global_load_lds((gp_t)g, (lp_t)l, 16, 0, 0);
}

__device__ __forceinline__ float bf2f(u16 u) {
    u32 t = ((u32)u) << 16;
    float f; __builtin_memcpy(&f, &t, 4); return f;
}
__device__ __forceinline__ u16 f2bf(float f) {   // RTNE
    u32 u; __builtin_memcpy(&u, &f, 4);
    u += 0x7fffu + ((u >> 16) & 1u);
    return (u16)(u >> 16);
}
__device__ __forceinline__ u32 packbf(float lo, float hi_) {
    __hip_bfloat162 h = __float22bfloat162_rn(float2{lo, hi_});
    u32 r; __builtin_memcpy(&r, &h, 4); return r;
}

__device__ __forceinline__ float exp2_fast(float x) { return __builtin_amdgcn_exp2f(x); }

#if __has_builtin(__builtin_amdgcn_permlane32_swap)
__device__ __forceinline__ void plswap(u32& a, u32& bb) {
    u32x2 r = __builtin_amdgcn_permlane32_swap(a, bb, false, false);
    a = r.x; bb = r.y;
}
#else
__device__ __forceinline__ void plswap(u32& a, u32& bb) {
    int hi = (threadIdx.x >> 5) & 1;
    u32 ra = (u32)__shfl_xor((int)a, 32);
    u32 rb = (u32)__shfl_xor((int)bb, 32);
    u32 na = hi ? rb : a;
    u32 nb = hi ? bb : ra;
    a = na; bb = nb;
}
#endif

// ---------------- fused fp32 -> bf16 cast for x + 4 weights ----------------
__global__ __launch_bounds__(256)
void cvt_all_kernel(const float* __restrict__ x,
                    const float* __restrict__ wq, const float* __restrict__ wk,
                    const float* __restrict__ wv, const float* __restrict__ wo,
                    u16* __restrict__ xb, u16* __restrict__ wqb, u16* __restrict__ wkb,
                    u16* __restrict__ wvb, u16* __restrict__ wob)
{
    const size_t MD = (size_t)M_TOT * D;
    const size_t WD = (size_t)D * D;       // 2^20
    size_t i = ((size_t)blockIdx.x * 256 + threadIdx.x) * 8;
    const float* src; u16* dst; size_t off;
    if (i < MD) { src = x; dst = xb; off = i; }
    else {
        size_t j = i - MD;
        int wsel = (int)(j >> 20);
        off = j & (WD - 1);
        if      (wsel == 0) { src = wq; dst = wqb; }
        else if (wsel == 1) { src = wk; dst = wkb; }
        else if (wsel == 2) { src = wv; dst = wvb; }
        else                { src = wo; dst = wob; }
    }
    float4 a = *(const float4*)(src + off);
    float4 b = *(const float4*)(src + off + 4);
    union { u16 u[8]; bf16x8 v; } o;
    o.u[0] = f2bf(a.x); o.u[1] = f2bf(a.y); o.u[2] = f2bf(a.z); o.u[3] = f2bf(a.w);
    o.u[4] = f2bf(b.x); o.u[5] = f2bf(b.y); o.u[6] = f2bf(b.z); o.u[7] = f2bf(b.w);
    *(bf16x8*)(dst + off) = o.v;
}

// ---------------- 256x256 deep-pipelined QKV GEMM (unchanged from R17) -----
#define NKT 32   // 1024/32

__global__ __launch_bounds__(512)
void gemm256_qkv(const u16* __restrict__ X,
                 const u16* __restrict__ W0, const u16* __restrict__ W1, const u16* __restrict__ W2,
                 u16* __restrict__ Y0, u16* __restrict__ Y1, u16* __restrict__ Y2,
                 const float* __restrict__ cosT, const float* __restrict__ sinT)
{
    __shared__ __align__(16) u16 lds[65536];   // 4 slots x (A 8192 + B 8192) u16

    const u16* Wm = (blockIdx.z == 0) ? W0 : (blockIdx.z == 1) ? W1 : W2;
    u16* Y        = (blockIdx.z == 0) ? Y0 : (blockIdx.z == 1) ? Y1 : Y2;

    const int t  = threadIdx.x;
    const int w  = t >> 6, ll = t & 63;
    const int lc = ll & 15, g = ll >> 4;
    const int wr = w >> 2, wc = w & 3;
    const int m0 = blockIdx.x * 256, n0 = blockIdx.y * 256;

    const int srow   = t >> 2;                         // 0..127
    const int scolsw = 8 * ((t & 3) ^ ((t >> 3) & 3)); // pre-swizzled src col (bf16)

    const u16* Xa = X + (size_t)m0 * D;
    const u16* Wa = Wm + (size_t)n0 * D;

    int offA[8], offB[4];
    #pragma unroll
    for (int i = 0; i < 8; ++i) {
        int row = wr * 128 + i * 16 + lc;
        offA[i] = row * 32 + ((g ^ ((row >> 1) & 3)) << 3);
    }
    #pragma unroll
    for (int j = 0; j < 4; ++j) {
        int row = wc * 64 + j * 16 + lc;
        offB[j] = row * 32 + ((g ^ ((row >> 1) & 3)) << 3);
    }

    f32x4 acc[8][4];
    #pragma unroll
    for (int i = 0; i < 8; ++i)
        #pragma unroll
        for (int j = 0; j < 4; ++j)
            acc[i][j] = (f32x4){0.f, 0.f, 0.f, 0.f};

    #pragma unroll
    for (int kt = 0; kt < 3; ++kt) {
        const u16* xs = Xa + (size_t)srow * D + kt * 32 + scolsw;
        gload_lds16(xs,           &lds[kt * 16384 + w * 512]);
        gload_lds16(xs + 128 * D, &lds[kt * 16384 + 4096 + w * 512]);
        const u16* ws = Wa + (size_t)srow * D + kt * 32 + scolsw;
        gload_lds16(ws,           &lds[kt * 16384 + 8192 + w * 512]);
        gload_lds16(ws + 128 * D, &lds[kt * 16384 + 8192 + 4096 + w * 512]);
    }
    asm volatile("s_waitcnt vmcnt(8)" ::: "memory");
    __builtin_amdgcn_s_barrier();

    auto body = [&](int kt, bool do_stage) {
        const int s = kt & 3;
        const u16* As = &lds[s * 16384];
        const u16* Bs = &lds[s * 16384 + 8192];
        const int kn = kt + 3;
        const int sn = kn & 3;
        if (do_stage) {
            const u16* xs = Xa + (size_t)srow * D + kn * 32 + scolsw;
            gload_lds16(xs,           &lds[sn * 16384 + w * 512]);
            gload_lds16(xs + 128 * D, &lds[sn * 16384 + 4096 + w * 512]);
        }
        bf16x8 bfr[4];
        #pragma unroll
        for (int j = 0; j < 4; ++j)
            bfr[j] = *(const bf16x8*)&Bs[offB[j]];
        bf16x8 afr[4];
        #pragma unroll
        for (int i = 0; i < 4; ++i)
            afr[i] = *(const bf16x8*)&As[offA[i]];
        #pragma unroll
        for (int i = 0; i < 4; ++i)
            #pragma unroll
            for (int j = 0; j < 4; ++j)
                acc[i][j] = __builtin_amdgcn_mfma_f32_16x16x32_bf16(afr[i], bfr[j], acc[i][j], 0, 0, 0);
        if (do_stage) {
            const u16* ws = Wa + (size_t)srow * D + kn * 32 + scolsw;
            gload_lds16(ws,           &lds[sn * 16384 + 8192 + w * 512]);
            gload_lds16(ws + 128 * D, &lds[sn * 16384 + 8192 + 4096 + w * 512]);
        }
        #pragma unroll
        for (int i = 0; i < 4; ++i)
            afr[i] = *(const bf16x8*)&As[offA[i + 4]];
        #pragma unroll
        for (int i = 0; i < 4; ++i)
            #pragma unroll
            for (int j = 0; j < 4; ++j)
                acc[i + 4][j] = __builtin_amdgcn_mfma_f32_16x16x32_bf16(afr[i], bfr[j], acc[i + 4][j], 0, 0, 0);
    };

    for (int kt = 0; kt < NKT - 3; ++kt) {
        body(kt, true);
        asm volatile("s_waitcnt vmcnt(8)" ::: "memory");
        __builtin_amdgcn_s_barrier();
    }
    body(NKT - 3, false);
    asm volatile("s_waitcnt vmcnt(4)" ::: "memory");
    __builtin_amdgcn_s_barrier();
    body(NKT - 2, false);
    asm volatile("s_waitcnt vmcnt(0)" ::: "memory");
    __builtin_amdgcn_s_barrier();
    body(NKT - 1, false);

    if (blockIdx.z < 2) {
        const float scale = (blockIdx.z == 0) ? (0.125f * 1.44269504f) : 1.0f;
        #pragma unroll
        for (int i = 0; i < 8; ++i)
            #pragma unroll
            for (int r = 0; r < 4; ++r) {
                int row = m0 + wr * 128 + i * 16 + g * 4 + r;
                int s = row & (S - 1);
                #pragma unroll
                for (int jh = 0; jh < 2; ++jh) {
                    float c  = cosT[s * DH + jh * 16 + lc];
                    float sn = sinT[s * DH + jh * 16 + lc];
                    float a0 = acc[i][jh][r], a1 = acc[i][jh + 2][r];
                    size_t base = (size_t)row * D + n0 + wc * 64;
                    Y[base + jh * 16 + lc]       = f2bf((a0 * c - a1 * sn) * scale);
                    Y[base + (jh + 2) * 16 + lc] = f2bf((a1 * c + a0 * sn) * scale);
                }
            }
    } else {
        #pragma unroll
        for (int i = 0; i < 8; ++i)
            #pragma unroll
            for (int j = 0; j < 4; ++j) {
                int row = m0 + wr * 128 + i * 16 + g * 4;      // token index (r=0)
                int col = n0 + wc * 64 + j * 16 + lc;          // feature index
                int bt = row >> 11, s = row & (S - 1);
                size_t vtrow = (size_t)(bt * 16 + (col >> 6)) * 64 + (col & 63);
                u32 w0 = packbf(acc[i][j][0], acc[i][j][1]);
                u32 w1 = packbf(acc[i][j][2], acc[i][j][3]);
                u32x2 pr; pr.x = w0; pr.y = w1;
                *(u32x2*)&Y[vtrow * S + s] = pr;
            }
    }
}

// ---------------- 128x128 deep-pipelined output projection (unchanged) -----
__global__ __launch_bounds__(256)
void gemm128_wo(const u16* __restrict__ X, const u16* __restrict__ Wm,
                float* __restrict__ Y)
{
    __shared__ __align__(16) u16 lds[32768];   // 4 slots x (A 4096 + B 4096) u16

    const int t  = threadIdx.x;
    const int w  = t >> 6, ll = t & 63;
    const int lc = ll & 15, g = ll >> 4;
    const int wr = w >> 1, wc = w & 1;
    const int m0 = blockIdx.x * 128, n0 = blockIdx.y * 128;

    const int srow   = t >> 2;                         // 0..63
    const int scolsw = 8 * ((t & 3) ^ ((t >> 3) & 3)); // pre-swizzled src col

    const u16* Xa = X + (size_t)m0 * D;
    const u16* Wa = Wm + (size_t)n0 * D;

    int offA[4], offB[4];
    #pragma unroll
    for (int i = 0; i < 4; ++i) {
        int row = wr * 64 + i * 16 + lc;
        offA[i] = row * 32 + ((g ^ ((row >> 1) & 3)) << 3);
    }
    #pragma unroll
    for (int j = 0; j < 4; ++j) {
        int row = wc * 64 + j * 16 + lc;
        offB[j] = row * 32 + ((g ^ ((row >> 1) & 3)) << 3);
    }

    f32x4 acc[4][4];
    #pragma unroll
    for (int i = 0; i < 4; ++i)
        #pragma unroll
        for (int j = 0; j < 4; ++j)
            acc[i][j] = (f32x4){0.f, 0.f, 0.f, 0.f};

    #pragma unroll
    for (int kt = 0; kt < 3; ++kt) {
        const u16* xs = Xa + (size_t)srow * D + kt * 32 + scolsw;
        gload_lds16(xs,          &lds[kt * 8192 + w * 512]);
        gload_lds16(xs + 64 * D, &lds[kt * 8192 + 2048 + w * 512]);
        const u16* ws = Wa + (size_t)srow * D + kt * 32 + scolsw;
        gload_lds16(ws,          &lds[kt * 8192 + 4096 + w * 512]);
        gload_lds16(ws + 64 * D, &lds[kt * 8192 + 4096 + 2048 + w * 512]);
    }
    asm volatile("s_waitcnt vmcnt(8)" ::: "memory");
    __builtin_amdgcn_s_barrier();

    auto body = [&](int kt, bool do_stage) {
        const int s = kt & 3;
        const u16* As = &lds[s * 8192];
        const u16* Bs = &lds[s * 8192 + 4096];
        const int kn = kt + 3;
        const int sn = kn & 3;
        if (do_stage) {
            const u16* xs = Xa + (size_t)srow * D + kn * 32 + scolsw;
            gload_lds16(xs,          &lds[sn * 8192 + w * 512]);
            gload_lds16(xs + 64 * D, &lds[sn * 8192 + 2048 + w * 512]);
        }
        bf16x8 bfr[4];
        #pragma unroll
        for (int j = 0; j < 4; ++j)
            bfr[j] = *(const bf16x8*)&Bs[offB[j]];
        bf16x8 afr[2];
        afr[0] = *(const bf16x8*)&As[offA[0]];
        afr[1] = *(const bf16x8*)&As[offA[1]];
        #pragma unroll
        for (int i = 0; i < 2; ++i)
            #pragma unroll
            for (int j = 0; j < 4; ++j)
                acc[i][j] = __builtin_amdgcn_mfma_f32_16x16x32_bf16(afr[i], bfr[j], acc[i][j], 0, 0, 0);
        if (do_stage) {
            const u16* ws = Wa + (size_t)srow * D + kn * 32 + scolsw;
            gload_lds16(ws,          &lds[sn * 8192 + 4096 + w * 512]);
            gload_lds16(ws + 64 * D, &lds[sn * 8192 + 4096 + 2048 + w * 512]);
        }
        afr[0] = *(const bf16x8*)&As[offA[2]];
        afr[1] = *(const bf16x8*)&As[offA[3]];
        #pragma unroll
        for (int i = 0; i < 2; ++i)
            #pragma unroll
            for (int j = 0; j < 4; ++j)
                acc[i + 2][j] = __builtin_amdgcn_mfma_f32_16x16x32_bf16(afr[i], bfr[j], acc[i + 2][j], 0, 0, 0);
    };

    for (int kt = 0; kt < NKT - 3; ++kt) {
        body(kt, true);
        asm volatile("s_waitcnt vmcnt(8)" ::: "memory");
        __builtin_amdgcn_s_barrier();
    }
    body(NKT - 3, false);
    asm volatile("s_waitcnt vmcnt(4)" ::: "memory");
    __builtin_amdgcn_s_barrier();
    body(NKT - 2, false);
    asm volatile("s_waitcnt vmcnt(0)" ::: "memory");
    __builtin_amdgcn_s_barrier();
    body(NKT - 1, false);

    #pragma unroll
    for (int i = 0; i < 4; ++i)
        #pragma unroll
        for (int j = 0; j < 4; ++j)
            #pragma unroll
            for (int r = 0; r < 4; ++r) {
                int row = m0 + wr * 64 + i * 16 + g * 4 + r;
                int col = n0 + wc * 64 + j * 16 + lc;
                Y[(size_t)row * D + col] = acc[i][j][r];
            }
}

// ---------------- MFMA flash attention: 4-slot counted-vmcnt pipeline ------
// KVT=64 so a tile-slot = K 8KB + V 8KB = 16KB; 4 slots = 64KB (2 blocks/CU).
// Both K and V tiles are [64 rows][128B] with the 8-slot swizzle (staging
// scol = ((t&7)^((t>>3)&7))<<3, read ^(q&7)<<4). FIFO identical to gemm256:
// 4 loads/tile/thread, prologue 3 tiles, steady vmcnt(8), taper 8->4->0.
#define QBLK 256
#define KVT2 64
#define NTT (S / KVT2)   // 32

__global__ __launch_bounds__(256, 2)
void attn_mfma(const u16* __restrict__ Q, const u16* __restrict__ Kg,
               const u16* __restrict__ Vt, u16* __restrict__ CTX)
{
    __shared__ __align__(16) u16 smem[32768];   // 4 slots x (K 4096 + V 4096) u16

    const int t  = threadIdx.x;
    const int w  = t >> 6;
    const int q  = t & 31;
    const int hi = (t >> 5) & 1;

    // XCD-chunked swizzle: 8 bh per XCD
    const int bid  = blockIdx.x;          // 0..511
    const int xcd  = bid & 7;
    const int slot = bid >> 3;            // 0..63
    const int bh   = xcd * 8 + (slot >> 3);
    const int qb   = slot & 7;
    const int b = bh >> 4, h = bh & 15;
    const int q0 = qb * QBLK;
    const int qbase = q0 + w * 64;

    // Q as B-fragments for 2 q-groups (pre-scaled by cs2 in the GEMM)
    bf16x8 qf[2][4];
    #pragma unroll
    for (int qg = 0; qg < 2; ++qg) {
        const u16* qp = &Q[(size_t)(b*S + qbase + qg*32 + q) * D + h*DH + hi*8];
        qf[qg][0] = *(const bf16x8*)(qp);
        qf[qg][1] = *(const bf16x8*)(qp + 16);
        qf[qg][2] = *(const bf16x8*)(qp + 32);
        qf[qg][3] = *(const bf16x8*)(qp + 48);
    }

    bf16x8 ones;
    {
        union { u16 u[8]; bf16x8 v; } ou;
        #pragma unroll
        for (int i = 0; i < 8; ++i) ou.u[i] = 0x3f80;   // bf16 1.0
        ones = ou.v;
    }

    f32x16 po[4], lsum[2], zv;
    #pragma unroll
    for (int i = 0; i < 16; ++i) {
        po[0][i] = 0.f; po[1][i] = 0.f; po[2][i] = 0.f; po[3][i] = 0.f;
        lsum[0][i] = 0.f; lsum[1][i] = 0.f; zv[i] = 0.f;
    }

    // staging geometry: 256 thr x 16B = 32 rows of 128B per issue
    const int srow = t >> 3;                                // 0..31
    const int scol = ((t & 7) ^ ((t >> 3) & 7)) << 3;       // pre-swizzled, u16
    const int rsw  = (q & 7) << 4;                          // read swizzle (bytes)

    const u16* kg = Kg + ((size_t)(b * S) + srow) * D + (size_t)h * DH + scol;
    const u16* vg = Vt + ((size_t)bh * DH + srow) * S + scol;

    #define STAGE(sl) do {                                       \
        gload_lds16(kg,          &smem[(sl)*8192 + w*512]);          \
        gload_lds16(kg + 32*D,   &smem[(sl)*8192 + 2048 + w*512]);   \
        gload_lds16(vg,          &smem[(sl)*8192 + 4096 + w*512]);   \
        gload_lds16(vg + 32*S,   &smem[(sl)*8192 + 4096 + 2048 + w*512]); \
        kg += (size_t)KVT2 * D; vg += KVT2; } while (0)

    auto body = [&](int kt, bool do_stage) {
        const int sl = kt & 3;
        const u16* Kl = &smem[sl * 8192];
        const u16* Vl = &smem[sl * 8192 + 4096];
        if (do_stage) { const int sn = (kt + 3) & 3; STAGE(sn); }
        #pragma unroll
        for (int c = 0; c < 2; ++c) {
            // ---- QK for keys c*32 .. c*32+31 ----
            f32x16 p0, p1;
            {
                const u16* kr = &Kl[(c*32 + q) << 6];
                bf16x8 k0 = *(const bf16x8*)&kr[((0*32 + hi*16) ^ rsw) >> 1];
                __builtin_amdgcn_s_setprio(1);
                p0 = __builtin_amdgcn_mfma_f32_32x32x16_bf16(k0, qf[0][0], zv, 0, 0, 0);
                p1 = __builtin_amdgcn_mfma_f32_32x32x16_bf16(k0, qf[1][0], zv, 0, 0, 0);
                #pragma unroll
                for (int cc = 1; cc < 4; ++cc) {
                    bf16x8 kf = *(const bf16x8*)&kr[((cc*32 + hi*16) ^ rsw) >> 1];
                    p0 = __builtin_amdgcn_mfma_f32_32x32x16_bf16(kf, qf[0][cc], p0, 0, 0, 0);
                    p1 = __builtin_amdgcn_mfma_f32_32x32x16_bf16(kf, qf[1][cc], p1, 0, 0, 0);
                }
                __builtin_amdgcn_s_setprio(0);
            }

            // ---- P = exp2(score), pack to bf16 fragments ----
            u32 W0[8], W1[8];
            #pragma unroll
            for (int j = 0; j < 8; ++j) {
                W0[j] = packbf(exp2_fast(p0[2*j]), exp2_fast(p0[2*j + 1]));
                W1[j] = packbf(exp2_fast(p1[2*j]), exp2_fast(p1[2*j + 1]));
            }
            plswap(W0[0], W0[2]); plswap(W0[1], W0[3]);
            plswap(W0[4], W0[6]); plswap(W0[5], W0[7]);
            plswap(W1[0], W1[2]); plswap(W1[1], W1[3]);
            plswap(W1[4], W1[6]); plswap(W1[5], W1[7]);
            bf16x8 pa0a, pa0b, pa1a, pa1b;
            {
                union { u32 u[4]; bf16x8 v; } pb;
                pb.u[0]=W0[0]; pb.u[1]=W0[1]; pb.u[2]=W0[2]; pb.u[3]=W0[3]; pa0a = pb.v;
                pb.u[0]=W0[4]; pb.u[1]=W0[5]; pb.u[2]=W0[6]; pb.u[3]=W0[7]; pa0b = pb.v;
                pb.u[0]=W1[0]; pb.u[1]=W1[1]; pb.u[2]=W1[2]; pb.u[3]=W1[3]; pa1a = pb.v;
                pb.u[0]=W1[4]; pb.u[1]=W1[5]; pb.u[2]=W1[6]; pb.u[3]=W1[7]; pa1b = pb.v;
            }

            // ---- lsum += ones^T x P ; po += Vt_frag x pa ----
            __builtin_amdgcn_s_setprio(1);
            lsum[0] = __builtin_amdgcn_mfma_f32_32x32x16_bf16(ones, pa0a, lsum[0], 0, 0, 0);
            lsum[1] = __builtin_amdgcn_mfma_f32_32x32x16_bf16(ones, pa1a, lsum[1], 0, 0, 0);
            lsum[0] = __builtin_amdgcn_mfma_f32_32x32x16_bf16(ones, pa0b, lsum[0], 0, 0, 0);
            lsum[1] = __builtin_amdgcn_mfma_f32_32x32x16_bf16(ones, pa1b, lsum[1], 0, 0, 0);
            #pragma unroll
            for (int kk = 0; kk < 2; ++kk) {
                int vb = ((c*64 + kk*32 + hi*16) ^ rsw) >> 1;
                bf16x8 v0 = *(const bf16x8*)&Vl[(q << 6) + vb];
                bf16x8 v1 = *(const bf16x8*)&Vl[((32 + q) << 6) + vb];
                bf16x8 pq0 = kk ? pa0b : pa0a;
                bf16x8 pq1 = kk ? pa1b : pa1a;
                po[0] = __builtin_amdgcn_mfma_f32_32x32x16_bf16(v0, pq0, po[0], 0, 0, 0);
                po[1] = __builtin_amdgcn_mfma_f32_32x32x16_bf16(v1, pq0, po[1], 0, 0, 0);
                po[2] = __builtin_amdgcn_mfma_f32_32x32x16_bf16(v0, pq1, po[2], 0, 0, 0);
                po[3] = __builtin_amdgcn_mfma_f32_32x32x16_bf16(v1, pq1, po[3], 0, 0, 0);
            }
            __builtin_amdgcn_s_setprio(0);
        }
    };

    // prologue: stage tiles 0,1,2
    STAGE(0); STAGE(1); STAGE(2);
    asm volatile("s_waitcnt vmcnt(8)" ::: "memory");   // tile 0 landed
    __builtin_amdgcn_s_barrier();

    for (int kt = 0; kt < NTT - 3; ++kt) {
        body(kt, true);
        asm volatile("s_waitcnt vmcnt(8)" ::: "memory");
        __builtin_amdgcn_s_barrier();
    }
    body(NTT - 3, false);
    asm volatile("s_waitcnt vmcnt(4)" ::: "memory");
    __builtin_amdgcn_s_barrier();
    body(NTT - 2, false);
    asm volatile("s_waitcnt vmcnt(0)" ::: "memory");
    __builtin_amdgcn_s_barrier();
    body(NTT - 1, false);
    #undef STAGE

    // ---- epilogue: per q-group normalize + transpose via wave-local LDS ----
    // Waves write only their own 4.6KB region (slots 0-1 area); other waves'
    // final compute reads slot 3 (offset 24576+) -- disjoint, no barrier race.
    u16* ow = &smem[w * 2304];   // 32 rows x 72 u16 per wave (wave-local)
    #pragma unroll
    for (int qg = 0; qg < 2; ++qg) {
        float inv = 1.f / lsum[qg][0];
        #pragma unroll
        for (int r = 0; r < 16; ++r) {
            int d0 = (r & 3) + 8 * (r >> 2) + 4 * hi;
            ow[q * 72 + d0]      = f2bf(po[qg*2 + 0][r] * inv);
            ow[q * 72 + 32 + d0] = f2bf(po[qg*2 + 1][r] * inv);
        }
        int row = (t & 63) >> 1, half = t & 1;
        const u16* orow = &ow[row * 72 + half * 32];
        u16* gp = &CTX[(size_t)(b*S + qbase + qg*32 + row) * D + h*DH + half * 32];
        #pragma unroll
        for (int i = 0; i < 4; ++i)
            *(bf16x8*)(gp + i * 8) = *(const bf16x8*)(orow + i * 8);
    }
}

extern "C" void kernel_launch(void* const* d_in, const int* in_sizes, int n_in,
                              void* d_out, int out_size, void* d_ws, size_t ws_size,
                              hipStream_t stream)
{
    const float* x    = (const float*)d_in[0];
    const float* cosT = (const float*)d_in[1];
    const float* sinT = (const float*)d_in[2];
    const float* wq   = (const float*)d_in[3];
    const float* wk   = (const float*)d_in[4];
    const float* wv   = (const float*)d_in[5];
    const float* wo   = (const float*)d_in[6];
    float* out = (float*)d_out;

    const size_t MD = (size_t)M_TOT * D;
    const size_t WD = (size_t)D * D;

    u16* xb   = (u16*)d_ws;
    u16* Qb   = xb + MD;
    u16* Kb   = Qb + MD;
    u16* Vtb  = Kb + MD;
    u16* CTXb = Vtb + MD;
    u16* wqb  = CTXb + MD;
    u16* wkb  = wqb + WD;
    u16* wvb  = wkb + WD;
    u16* wob  = wvb + WD;

    // 1. fused bf16 casts (x + 4 weights in one launch)
    cvt_all_kernel<<<(int)((MD + 4*WD) / 8 / 256), 256, 0, stream>>>(
        x, wq, wk, wv, wo, xb, wqb, wkb, wvb, wob);

    // 2. fused QKV projections, deep-pipelined 256^2 tile
    gemm256_qkv<<<dim3(M_TOT / 256, D / 256, 3), 512, 0, stream>>>(
        xb, wqb, wkb, wvb, Qb, Kb, Vtb, cosT, sinT);

    // 3. attention, deep-pipelined 4-slot KVT=64
    attn_mfma<<<dim3(M_TOT / QBLK * H), 256, 0, stream>>>(Qb, Kb, Vtb, CTXb);

    // 4. output projection, deep-pipelined 128^2 tile (fp32 out)
    gemm128_wo<<<dim3(M_TOT / 128, D / 128), 256, 0, stream>>>(
        CTXb, wob, out);
}

// Round 20
// 177.330 us; speedup vs baseline: 1.0050x; 1.0050x over previous
//
#include <hip/hip_runtime.h>
#include <hip/hip_bf16.h>
#include <stdint.h>

#define B 4
#define S 2048
#define D 1024
#define H 16
#define DH 64
#define M_TOT (B*S)
#define BH (B*H)

typedef unsigned short u16;
typedef unsigned int u32;
typedef __attribute__((ext_vector_type(4))) float f32x4;
typedef __attribute__((ext_vector_type(16))) float f32x16;
typedef __attribute__((ext_vector_type(8))) short bf16x8;
typedef __attribute__((ext_vector_type(2))) unsigned int u32x2;

typedef const __attribute__((address_space(1))) unsigned int* gp_t;
typedef __attribute__((address_space(3))) unsigned int* lp_t;

__device__ __forceinline__ void gload_lds16(const void* g, void* l) {
    __builtin_amdgcn_global_load_lds((gp_t)g, (lp_t)l, 16, 0, 0);
}

__device__ __forceinline__ float bf2f(u16 u) {
    u32 t = ((u32)u) << 16;
    float f; __builtin_memcpy(&f, &t, 4); return f;
}
__device__ __forceinline__ u16 f2bf(float f) {   // RTNE
    u32 u; __builtin_memcpy(&u, &f, 4);
    u += 0x7fffu + ((u >> 16) & 1u);
    return (u16)(u >> 16);
}
__device__ __forceinline__ u32 packbf(float lo, float hi_) {
    __hip_bfloat162 h = __float22bfloat162_rn(float2{lo, hi_});
    u32 r; __builtin_memcpy(&r, &h, 4); return r;
}

__device__ __forceinline__ float exp2_fast(float x) { return __builtin_amdgcn_exp2f(x); }

#if __has_builtin(__builtin_amdgcn_permlane32_swap)
__device__ __forceinline__ void plswap(u32& a, u32& bb) {
    u32x2 r = __builtin_amdgcn_permlane32_swap(a, bb, false, false);
    a = r.x; bb = r.y;
}
#else
__device__ __forceinline__ void plswap(u32& a, u32& bb) {
    int hi = (threadIdx.x >> 5) & 1;
    u32 ra = (u32)__shfl_xor((int)a, 32);
    u32 rb = (u32)__shfl_xor((int)bb, 32);
    u32 na = hi ? rb : a;
    u32 nb = hi ? bb : ra;
    a = na; bb = nb;
}
#endif

// ---------------- fused fp32 -> bf16 cast for x + 4 weights ----------------
__global__ __launch_bounds__(256)
void cvt_all_kernel(const float* __restrict__ x,
                    const float* __restrict__ wq, const float* __restrict__ wk,
                    const float* __restrict__ wv, const float* __restrict__ wo,
                    u16* __restrict__ xb, u16* __restrict__ wqb, u16* __restrict__ wkb,
                    u16* __restrict__ wvb, u16* __restrict__ wob)
{
    const size_t MD = (size_t)M_TOT * D;
    const size_t WD = (size_t)D * D;       // 2^20
    size_t i = ((size_t)blockIdx.x * 256 + threadIdx.x) * 8;
    const float* src; u16* dst; size_t off;
    if (i < MD) { src = x; dst = xb; off = i; }
    else {
        size_t j = i - MD;
        int wsel = (int)(j >> 20);
        off = j & (WD - 1);
        if      (wsel == 0) { src = wq; dst = wqb; }
        else if (wsel == 1) { src = wk; dst = wkb; }
        else if (wsel == 2) { src = wv; dst = wvb; }
        else                { src = wo; dst = wob; }
    }
    float4 a = *(const float4*)(src + off);
    float4 b = *(const float4*)(src + off + 4);
    union { u16 u[8]; bf16x8 v; } o;
    o.u[0] = f2bf(a.x); o.u[1] = f2bf(a.y); o.u[2] = f2bf(a.z); o.u[3] = f2bf(a.w);
    o.u[4] = f2bf(b.x); o.u[5] = f2bf(b.y); o.u[6] = f2bf(b.z); o.u[7] = f2bf(b.w);
    *(bf16x8*)(dst + off) = o.v;
}

// ---------------- 256x256 deep-pipelined QKV GEMM (R17, verified) ----------
#define NKT 32   // 1024/32

__global__ __launch_bounds__(512)
void gemm256_qkv(const u16* __restrict__ X,
                 const u16* __restrict__ W0, const u16* __restrict__ W1, const u16* __restrict__ W2,
                 u16* __restrict__ Y0, u16* __restrict__ Y1, u16* __restrict__ Y2,
                 const float* __restrict__ cosT, const float* __restrict__ sinT)
{
    __shared__ __align__(16) u16 lds[65536];   // 4 slots x (A 8192 + B 8192) u16

    const u16* Wm = (blockIdx.z == 0) ? W0 : (blockIdx.z == 1) ? W1 : W2;
    u16* Y        = (blockIdx.z == 0) ? Y0 : (blockIdx.z == 1) ? Y1 : Y2;

    const int t  = threadIdx.x;
    const int w  = t >> 6, ll = t & 63;
    const int lc = ll & 15, g = ll >> 4;
    const int wr = w >> 2, wc = w & 3;
    const int m0 = blockIdx.x * 256, n0 = blockIdx.y * 256;

    const int srow   = t >> 2;                         // 0..127
    const int scolsw = 8 * ((t & 3) ^ ((t >> 3) & 3)); // pre-swizzled src col (bf16)

    const u16* Xa = X + (size_t)m0 * D;
    const u16* Wa = Wm + (size_t)n0 * D;

    int offA[8], offB[4];
    #pragma unroll
    for (int i = 0; i < 8; ++i) {
        int row = wr * 128 + i * 16 + lc;
        offA[i] = row * 32 + ((g ^ ((row >> 1) & 3)) << 3);
    }
    #pragma unroll
    for (int j = 0; j < 4; ++j) {
        int row = wc * 64 + j * 16 + lc;
        offB[j] = row * 32 + ((g ^ ((row >> 1) & 3)) << 3);
    }

    f32x4 acc[8][4];
    #pragma unroll
    for (int i = 0; i < 8; ++i)
        #pragma unroll
        for (int j = 0; j < 4; ++j)
            acc[i][j] = (f32x4){0.f, 0.f, 0.f, 0.f};

    #pragma unroll
    for (int kt = 0; kt < 3; ++kt) {
        const u16* xs = Xa + (size_t)srow * D + kt * 32 + scolsw;
        gload_lds16(xs,           &lds[kt * 16384 + w * 512]);
        gload_lds16(xs + 128 * D, &lds[kt * 16384 + 4096 + w * 512]);
        const u16* ws = Wa + (size_t)srow * D + kt * 32 + scolsw;
        gload_lds16(ws,           &lds[kt * 16384 + 8192 + w * 512]);
        gload_lds16(ws + 128 * D, &lds[kt * 16384 + 8192 + 4096 + w * 512]);
    }
    asm volatile("s_waitcnt vmcnt(8)" ::: "memory");
    __builtin_amdgcn_s_barrier();

    auto body = [&](int kt, bool do_stage) {
        const int s = kt & 3;
        const u16* As = &lds[s * 16384];
        const u16* Bs = &lds[s * 16384 + 8192];
        const int kn = kt + 3;
        const int sn = kn & 3;
        if (do_stage) {
            const u16* xs = Xa + (size_t)srow * D + kn * 32 + scolsw;
            gload_lds16(xs,           &lds[sn * 16384 + w * 512]);
            gload_lds16(xs + 128 * D, &lds[sn * 16384 + 4096 + w * 512]);
        }
        bf16x8 bfr[4];
        #pragma unroll
        for (int j = 0; j < 4; ++j)
            bfr[j] = *(const bf16x8*)&Bs[offB[j]];
        bf16x8 afr[4];
        #pragma unroll
        for (int i = 0; i < 4; ++i)
            afr[i] = *(const bf16x8*)&As[offA[i]];
        #pragma unroll
        for (int i = 0; i < 4; ++i)
            #pragma unroll
            for (int j = 0; j < 4; ++j)
                acc[i][j] = __builtin_amdgcn_mfma_f32_16x16x32_bf16(afr[i], bfr[j], acc[i][j], 0, 0, 0);
        if (do_stage) {
            const u16* ws = Wa + (size_t)srow * D + kn * 32 + scolsw;
            gload_lds16(ws,           &lds[sn * 16384 + 8192 + w * 512]);
            gload_lds16(ws + 128 * D, &lds[sn * 16384 + 8192 + 4096 + w * 512]);
        }
        #pragma unroll
        for (int i = 0; i < 4; ++i)
            afr[i] = *(const bf16x8*)&As[offA[i + 4]];
        #pragma unroll
        for (int i = 0; i < 4; ++i)
            #pragma unroll
            for (int j = 0; j < 4; ++j)
                acc[i + 4][j] = __builtin_amdgcn_mfma_f32_16x16x32_bf16(afr[i], bfr[j], acc[i + 4][j], 0, 0, 0);
    };

    for (int kt = 0; kt < NKT - 3; ++kt) {
        body(kt, true);
        asm volatile("s_waitcnt vmcnt(8)" ::: "memory");
        __builtin_amdgcn_s_barrier();
    }
    body(NKT - 3, false);
    asm volatile("s_waitcnt vmcnt(4)" ::: "memory");
    __builtin_amdgcn_s_barrier();
    body(NKT - 2, false);
    asm volatile("s_waitcnt vmcnt(0)" ::: "memory");
    __builtin_amdgcn_s_barrier();
    body(NKT - 1, false);

    if (blockIdx.z < 2) {
        const float scale = (blockIdx.z == 0) ? (0.125f * 1.44269504f) : 1.0f;
        #pragma unroll
        for (int i = 0; i < 8; ++i)
            #pragma unroll
            for (int r = 0; r < 4; ++r) {
                int row = m0 + wr * 128 + i * 16 + g * 4 + r;
                int s = row & (S - 1);
                #pragma unroll
                for (int jh = 0; jh < 2; ++jh) {
                    float c  = cosT[s * DH + jh * 16 + lc];
                    float sn = sinT[s * DH + jh * 16 + lc];
                    float a0 = acc[i][jh][r], a1 = acc[i][jh + 2][r];
                    size_t base = (size_t)row * D + n0 + wc * 64;
                    Y[base + jh * 16 + lc]       = f2bf((a0 * c - a1 * sn) * scale);
                    Y[base + (jh + 2) * 16 + lc] = f2bf((a1 * c + a0 * sn) * scale);
                }
            }
    } else {
        #pragma unroll
        for (int i = 0; i < 8; ++i)
            #pragma unroll
            for (int j = 0; j < 4; ++j) {
                int row = m0 + wr * 128 + i * 16 + g * 4;      // token index (r=0)
                int col = n0 + wc * 64 + j * 16 + lc;          // feature index
                int bt = row >> 11, s = row & (S - 1);
                size_t vtrow = (size_t)(bt * 16 + (col >> 6)) * 64 + (col & 63);
                u32 w0 = packbf(acc[i][j][0], acc[i][j][1]);
                u32 w1 = packbf(acc[i][j][2], acc[i][j][3]);
                u32x2 pr; pr.x = w0; pr.y = w1;
                *(u32x2*)&Y[vtrow * S + s] = pr;
            }
    }
}

// ---------------- 128x128 deep-pipelined output projection (R18, verified) -
__global__ __launch_bounds__(256)
void gemm128_wo(const u16* __restrict__ X, const u16* __restrict__ Wm,
                float* __restrict__ Y)
{
    __shared__ __align__(16) u16 lds[32768];   // 4 slots x (A 4096 + B 4096) u16

    const int t  = threadIdx.x;
    const int w  = t >> 6, ll = t & 63;
    const int lc = ll & 15, g = ll >> 4;
    const int wr = w >> 1, wc = w & 1;
    const int m0 = blockIdx.x * 128, n0 = blockIdx.y * 128;

    const int srow   = t >> 2;                         // 0..63
    const int scolsw = 8 * ((t & 3) ^ ((t >> 3) & 3)); // pre-swizzled src col

    const u16* Xa = X + (size_t)m0 * D;
    const u16* Wa = Wm + (size_t)n0 * D;

    int offA[4], offB[4];
    #pragma unroll
    for (int i = 0; i < 4; ++i) {
        int row = wr * 64 + i * 16 + lc;
        offA[i] = row * 32 + ((g ^ ((row >> 1) & 3)) << 3);
    }
    #pragma unroll
    for (int j = 0; j < 4; ++j) {
        int row = wc * 64 + j * 16 + lc;
        offB[j] = row * 32 + ((g ^ ((row >> 1) & 3)) << 3);
    }

    f32x4 acc[4][4];
    #pragma unroll
    for (int i = 0; i < 4; ++i)
        #pragma unroll
        for (int j = 0; j < 4; ++j)
            acc[i][j] = (f32x4){0.f, 0.f, 0.f, 0.f};

    #pragma unroll
    for (int kt = 0; kt < 3; ++kt) {
        const u16* xs = Xa + (size_t)srow * D + kt * 32 + scolsw;
        gload_lds16(xs,          &lds[kt * 8192 + w * 512]);
        gload_lds16(xs + 64 * D, &lds[kt * 8192 + 2048 + w * 512]);
        const u16* ws = Wa + (size_t)srow * D + kt * 32 + scolsw;
        gload_lds16(ws,          &lds[kt * 8192 + 4096 + w * 512]);
        gload_lds16(ws + 64 * D, &lds[kt * 8192 + 4096 + 2048 + w * 512]);
    }
    asm volatile("s_waitcnt vmcnt(8)" ::: "memory");
    __builtin_amdgcn_s_barrier();

    auto body = [&](int kt, bool do_stage) {
        const int s = kt & 3;
        const u16* As = &lds[s * 8192];
        const u16* Bs = &lds[s * 8192 + 4096];
        const int kn = kt + 3;
        const int sn = kn & 3;
        if (do_stage) {
            const u16* xs = Xa + (size_t)srow * D + kn * 32 + scolsw;
            gload_lds16(xs,          &lds[sn * 8192 + w * 512]);
            gload_lds16(xs + 64 * D, &lds[sn * 8192 + 2048 + w * 512]);
        }
        bf16x8 bfr[4];
        #pragma unroll
        for (int j = 0; j < 4; ++j)
            bfr[j] = *(const bf16x8*)&Bs[offB[j]];
        bf16x8 afr[2];
        afr[0] = *(const bf16x8*)&As[offA[0]];
        afr[1] = *(const bf16x8*)&As[offA[1]];
        #pragma unroll
        for (int i = 0; i < 2; ++i)
            #pragma unroll
            for (int j = 0; j < 4; ++j)
                acc[i][j] = __builtin_amdgcn_mfma_f32_16x16x32_bf16(afr[i], bfr[j], acc[i][j], 0, 0, 0);
        if (do_stage) {
            const u16* ws = Wa + (size_t)srow * D + kn * 32 + scolsw;
            gload_lds16(ws,          &lds[sn * 8192 + 4096 + w * 512]);
            gload_lds16(ws + 64 * D, &lds[sn * 8192 + 4096 + 2048 + w * 512]);
        }
        afr[0] = *(const bf16x8*)&As[offA[2]];
        afr[1] = *(const bf16x8*)&As[offA[3]];
        #pragma unroll
        for (int i = 0; i < 2; ++i)
            #pragma unroll
            for (int j = 0; j < 4; ++j)
                acc[i + 2][j] = __builtin_amdgcn_mfma_f32_16x16x32_bf16(afr[i], bfr[j], acc[i + 2][j], 0, 0, 0);
    };

    for (int kt = 0; kt < NKT - 3; ++kt) {
        body(kt, true);
        asm volatile("s_waitcnt vmcnt(8)" ::: "memory");
        __builtin_amdgcn_s_barrier();
    }
    body(NKT - 3, false);
    asm volatile("s_waitcnt vmcnt(4)" ::: "memory");
    __builtin_amdgcn_s_barrier();
    body(NKT - 2, false);
    asm volatile("s_waitcnt vmcnt(0)" ::: "memory");
    __builtin_amdgcn_s_barrier();
    body(NKT - 1, false);

    #pragma unroll
    for (int i = 0; i < 4; ++i)
        #pragma unroll
        for (int j = 0; j < 4; ++j)
            #pragma unroll
            for (int r = 0; r < 4; ++r) {
                int row = m0 + wr * 64 + i * 16 + g * 4 + r;
                int col = n0 + wc * 64 + j * 16 + lc;
                Y[(size_t)row * D + col] = acc[i][j][r];
            }
}

// ---------------- MFMA flash attention (R9 structure: best measured) -------
// 256 threads = 4 waves x 64 q-rows; 128-key tiles, 4 serial 32-key chunks
// (QK -> exp/pack -> lsum+PV), double-buffered 32KB K+V staging.
#define QBLK 256
#define KVT 128
#define NT (S / KVT)

__global__ __launch_bounds__(256, 2)
void attn_mfma(const u16* __restrict__ Q, const u16* __restrict__ Kg,
               const u16* __restrict__ Vt, u16* __restrict__ CTX)
{
    __shared__ __align__(16) u16 smem[32768];   // 2 x (K 16KB + V 16KB)

    const int t  = threadIdx.x;
    const int w  = t >> 6;
    const int q  = t & 31;
    const int hi = (t >> 5) & 1;

    // XCD-chunked swizzle: 8 bh per XCD
    const int bid  = blockIdx.x;          // 0..511
    const int xcd  = bid & 7;
    const int slot = bid >> 3;            // 0..63
    const int bh   = xcd * 8 + (slot >> 3);
    const int qb   = slot & 7;
    const int b = bh >> 4, h = bh & 15;
    const int q0 = qb * QBLK;
    const int qbase = q0 + w * 64;

    // Q as B-fragments for 2 q-groups
    bf16x8 qf[2][4];
    #pragma unroll
    for (int qg = 0; qg < 2; ++qg) {
        const u16* qp = &Q[(size_t)(b*S + qbase + qg*32 + q) * D + h*DH + hi*8];
        qf[qg][0] = *(const bf16x8*)(qp);
        qf[qg][1] = *(const bf16x8*)(qp + 16);
        qf[qg][2] = *(const bf16x8*)(qp + 32);
        qf[qg][3] = *(const bf16x8*)(qp + 48);
    }

    bf16x8 ones;
    {
        union { u16 u[8]; bf16x8 v; } ou;
        #pragma unroll
        for (int i = 0; i < 8; ++i) ou.u[i] = 0x3f80;   // bf16 1.0
        ones = ou.v;
    }

    f32x16 po[4], lsum[2], zv;
    #pragma unroll
    for (int i = 0; i < 16; ++i) {
        po[0][i] = 0.f; po[1][i] = 0.f; po[2][i] = 0.f; po[3][i] = 0.f;
        lsum[0][i] = 0.f; lsum[1][i] = 0.f; zv[i] = 0.f;
    }

    // K staging geometry (128B rows): 8 lanes/row
    const int ksrow = t >> 3;                                 // 0..31
    const int kscol = (((t & 7) << 4) ^ ((ksrow & 7) << 4)) >> 1;
    // V staging geometry (256B rows): 16 lanes/row, pre-swizzled source col
    const int vsrow = t >> 4;                                 // 0..15
    const int vscol = (((t & 15) ^ (vsrow & 15)) << 3);       // u16 units
    const int rsw  = (q & 7) << 4;    // K read swizzle (bytes)
    const int vsw  = (q & 15) << 4;   // V read swizzle (bytes)

    u16* buf0 = smem;
    u16* buf1 = smem + 16384;

    const u16* kg = Kg + ((size_t)(b * S) + ksrow) * D + (size_t)h * DH + kscol;
    const u16* vg = Vt + ((size_t)bh * DH + vsrow) * S + vscol;

    #define STAGE(dst) do {                                         \
        gload_lds16(kg,           (dst) + 0*2048 + w*512);          \
        gload_lds16(kg + 32*D,    (dst) + 1*2048 + w*512);          \
        gload_lds16(kg + 64*D,    (dst) + 2*2048 + w*512);          \
        gload_lds16(kg + 96*D,    (dst) + 3*2048 + w*512);          \
        gload_lds16(vg,           (dst) + 8192 + 0*2048 + w*512);   \
        gload_lds16(vg + 16*S,    (dst) + 8192 + 1*2048 + w*512);   \
        gload_lds16(vg + 32*S,    (dst) + 8192 + 2*2048 + w*512);   \
        gload_lds16(vg + 48*S,    (dst) + 8192 + 3*2048 + w*512);   \
        kg += (size_t)KVT * D; vg += KVT; } while (0)

    auto compute = [&](const u16* base) {
        const u16* Kl = base;
        const u16* Vl = base + 8192;
        #pragma unroll
        for (int c = 0; c < 4; ++c) {
            // ---- QK for keys c*32 .. c*32+31 ----
            f32x16 p0, p1;
            {
                const u16* kr = &Kl[(c*32 + q) << 6];
                bf16x8 k0 = *(const bf16x8*)&kr[((0*32 + hi*16) ^ rsw) >> 1];
                __builtin_amdgcn_s_setprio(1);
                p0 = __builtin_amdgcn_mfma_f32_32x32x16_bf16(k0, qf[0][0], zv, 0, 0, 0);
                p1 = __builtin_amdgcn_mfma_f32_32x32x16_bf16(k0, qf[1][0], zv, 0, 0, 0);
                #pragma unroll
                for (int cc = 1; cc < 4; ++cc) {
                    bf16x8 kf = *(const bf16x8*)&kr[((cc*32 + hi*16) ^ rsw) >> 1];
                    p0 = __builtin_amdgcn_mfma_f32_32x32x16_bf16(kf, qf[0][cc], p0, 0, 0, 0);
                    p1 = __builtin_amdgcn_mfma_f32_32x32x16_bf16(kf, qf[1][cc], p1, 0, 0, 0);
                }
                __builtin_amdgcn_s_setprio(0);
            }

            // ---- P = exp2(score), pack to bf16 fragments ----
            u32 W0[8], W1[8];
            #pragma unroll
            for (int j = 0; j < 8; ++j) {
                W0[j] = packbf(exp2_fast(p0[2*j]), exp2_fast(p0[2*j + 1]));
                W1[j] = packbf(exp2_fast(p1[2*j]), exp2_fast(p1[2*j + 1]));
            }
            plswap(W0[0], W0[2]); plswap(W0[1], W0[3]);
            plswap(W0[4], W0[6]); plswap(W0[5], W0[7]);
            plswap(W1[0], W1[2]); plswap(W1[1], W1[3]);
            plswap(W1[4], W1[6]); plswap(W1[5], W1[7]);
            bf16x8 pa0a, pa0b, pa1a, pa1b;
            {
                union { u32 u[4]; bf16x8 v; } pb;
                pb.u[0]=W0[0]; pb.u[1]=W0[1]; pb.u[2]=W0[2]; pb.u[3]=W0[3]; pa0a = pb.v;
                pb.u[0]=W0[4]; pb.u[1]=W0[5]; pb.u[2]=W0[6]; pb.u[3]=W0[7]; pa0b = pb.v;
                pb.u[0]=W1[0]; pb.u[1]=W1[1]; pb.u[2]=W1[2]; pb.u[3]=W1[3]; pa1a = pb.v;
                pb.u[0]=W1[4]; pb.u[1]=W1[5]; pb.u[2]=W1[6]; pb.u[3]=W1[7]; pa1b = pb.v;
            }

            // ---- lsum += ones^T x P ; po += Vt_frag x pa ----
            __builtin_amdgcn_s_setprio(1);
            lsum[0] = __builtin_amdgcn_mfma_f32_32x32x16_bf16(ones, pa0a, lsum[0], 0, 0, 0);
            lsum[1] = __builtin_amdgcn_mfma_f32_32x32x16_bf16(ones, pa1a, lsum[1], 0, 0, 0);
            lsum[0] = __builtin_amdgcn_mfma_f32_32x32x16_bf16(ones, pa0b, lsum[0], 0, 0, 0);
            lsum[1] = __builtin_amdgcn_mfma_f32_32x32x16_bf16(ones, pa1b, lsum[1], 0, 0, 0);
            #pragma unroll
            for (int kk = 0; kk < 2; ++kk) {
                int vb = ((c*64 + kk*32 + hi*16) ^ vsw) >> 1;
                bf16x8 v0 = *(const bf16x8*)&Vl[(q << 7) + vb];
                bf16x8 v1 = *(const bf16x8*)&Vl[((32 + q) << 7) + vb];
                bf16x8 pq0 = kk ? pa0b : pa0a;
                bf16x8 pq1 = kk ? pa1b : pa1a;
                po[0] = __builtin_amdgcn_mfma_f32_32x32x16_bf16(v0, pq0, po[0], 0, 0, 0);
                po[1] = __builtin_amdgcn_mfma_f32_32x32x16_bf16(v1, pq0, po[1], 0, 0, 0);
                po[2] = __builtin_amdgcn_mfma_f32_32x32x16_bf16(v0, pq1, po[2], 0, 0, 0);
                po[3] = __builtin_amdgcn_mfma_f32_32x32x16_bf16(v1, pq1, po[3], 0, 0, 0);
            }
            __builtin_amdgcn_s_setprio(0);
        }
    };

    // prologue: stage tile 0
    STAGE(buf0);
    asm volatile("s_waitcnt vmcnt(0)" ::: "memory");
    __builtin_amdgcn_s_barrier();

    for (int ti = 0; ti < NT; ti += 2) {
        STAGE(buf1);                       // tile ti+1
        compute(buf0);                     // tile ti
        asm volatile("s_waitcnt vmcnt(0)" ::: "memory");
        __builtin_amdgcn_s_barrier();
        if (ti < NT - 2) STAGE(buf0);      // tile ti+2
        compute(buf1);                     // tile ti+1
        asm volatile("s_waitcnt vmcnt(0)" ::: "memory");
        __builtin_amdgcn_s_barrier();
    }
    #undef STAGE

    // ---- epilogue: per q-group normalize + transpose via wave-local LDS ----
    u16* ow = &smem[w * 2304];   // 32 rows x 72 u16 per wave (wave-local)
    #pragma unroll
    for (int qg = 0; qg < 2; ++qg) {
        float inv = 1.f / lsum[qg][0];
        #pragma unroll
        for (int r = 0; r < 16; ++r) {
            int d0 = (r & 3) + 8 * (r >> 2) + 4 * hi;
            ow[q * 72 + d0]      = f2bf(po[qg*2 + 0][r] * inv);
            ow[q * 72 + 32 + d0] = f2bf(po[qg*2 + 1][r] * inv);
        }
        int row = (t & 63) >> 1, half = t & 1;
        const u16* orow = &ow[row * 72 + half * 32];
        u16* gp = &CTX[(size_t)(b*S + qbase + qg*32 + row) * D + h*DH + half * 32];
        #pragma unroll
        for (int i = 0; i < 4; ++i)
            *(bf16x8*)(gp + i * 8) = *(const bf16x8*)(orow + i * 8);
    }
}

extern "C" void kernel_launch(void* const* d_in, const int* in_sizes, int n_in,
                              void* d_out, int out_size, void* d_ws, size_t ws_size,
                              hipStream_t stream)
{
    const float* x    = (const float*)d_in[0];
    const float* cosT = (const float*)d_in[1];
    const float* sinT = (const float*)d_in[2];
    const float* wq   = (const float*)d_in[3];
    const float* wk   = (const float*)d_in[4];
    const float* wv   = (const float*)d_in[5];
    const float* wo   = (const float*)d_in[6];
    float* out = (float*)d_out;

    const size_t MD = (size_t)M_TOT * D;
    const size_t WD = (size_t)D * D;

    u16* xb   = (u16*)d_ws;
    u16* Qb   = xb + MD;
    u16* Kb   = Qb + MD;
    u16* Vtb  = Kb + MD;
    u16* CTXb = Vtb + MD;
    u16* wqb  = CTXb + MD;
    u16* wkb  = wqb + WD;
    u16* wvb  = wkb + WD;
    u16* wob  = wvb + WD;

    // 1. fused bf16 casts (x + 4 weights in one launch)
    cvt_all_kernel<<<(int)((MD + 4*WD) / 8 / 256), 256, 0, stream>>>(
        x, wq, wk, wv, wo, xb, wqb, wkb, wvb, wob);

    // 2. fused QKV projections, deep-pipelined 256^2 tile
    gemm256_qkv<<<dim3(M_TOT / 256, D / 256, 3), 512, 0, stream>>>(
        xb, wqb, wkb, wvb, Qb, Kb, Vtb, cosT, sinT);

    // 3. attention (R9 structure: best measured)
    attn_mfma<<<dim3(M_TOT / QBLK * H), 256, 0, stream>>>(Qb, Kb, Vtb, CTXb);

    // 4. output projection, deep-pipelined 128^2 tile (fp32 out)
    gemm128_wo<<<dim3(M_TOT / 128, D / 128), 256, 0, stream>>>(
        CTXb, wob, out);
}